// Round 1
// 773.929 us; speedup vs baseline: 1.1338x; 1.1338x over previous
//
#include <hip/hip_runtime.h>
#include <float.h>
#include <math.h>

// Decoder3: ragged maxpool -> a; then T=8 sequential fused GRU-decoder steps.
// B=128 T=8 E=52 S=2048 R=512 L=4.
// Outputs (f32, concat): dec_output[T*B] | dec_prob[T*B*L] | disc_input[T*B*L] | kl_input[T*B]
//
// R1 restructure: k_step GEMM was L1-return-BW bound (462 scalar dword loads/wave,
// 1.89 MB/CU/step). Now: quad-packed dwordx4 weights + 4-batch register tile per wave
// (weights read once per CU: 473 KB/step) + h staged in LDS + 16-way K-split with
// LDS tree reduction.

#define B_ 128
#define T_ 8
#define E_ 52
#define S_ 2048
#define R_ 512
#define L_ 4
#define GR_ 1536   // 3R
#define KX_ 104    // 2E
#define NCHUNK 16
#define SCHUNK (S_ / NCHUNK)   // 128
#define NQ_ 154    // merged K=616 in quads of 4
#define XQ_ 26     // x-part quads (104/4); quads >= XQ_ are h-part

__device__ __constant__ int c_remap[4] = {175, 176, 44, 173};

__device__ __forceinline__ float sigmoidf(float x) { return 1.0f / (1.0f + expf(-x)); }
__device__ __forceinline__ float dot4(float4 w, float4 x, float a) {
    a = fmaf(w.x, x.x, a);
    a = fmaf(w.y, x.y, a);
    a = fmaf(w.z, x.z, a);
    a = fmaf(w.w, x.w, a);
    return a;
}

// ---------------- Phase 1: ragged max-pool (partial, chunked over S) ----------------
__global__ void k_maxpool(const float* __restrict__ enc, const int* __restrict__ enc_len,
                          float4* __restrict__ partial) {
    int c = blockIdx.x;
    int b = blockIdx.y;
    int t = threadIdx.x;  // 0..127
    int len = enc_len[b];
    int s0 = c * SCHUNK;
    int s1 = min(s0 + SCHUNK, len);
    float4 m = make_float4(-FLT_MAX, -FLT_MAX, -FLT_MAX, -FLT_MAX);
    const float4* base = (const float4*)(enc + (size_t)b * S_ * R_);
    for (int s = s0; s < s1; ++s) {
        float4 v = base[(size_t)s * (R_ / 4) + t];
        m.x = fmaxf(m.x, v.x);
        m.y = fmaxf(m.y, v.y);
        m.z = fmaxf(m.z, v.z);
        m.w = fmaxf(m.w, v.w);
    }
    partial[((size_t)b * NCHUNK + c) * (R_ / 4) + t] = m;
}

// ---------------- Phase 1b: reduce partials + a = code_pool @ W_fc.T ----------------
__global__ void k_pool_a(const float* __restrict__ partial, const float* __restrict__ W_fc,
                         float* __restrict__ a_out) {
    int b = blockIdx.x;
    int tid = threadIdx.x;
    __shared__ float cp[R_];
    for (int r = tid; r < R_; r += 256) {
        float m = -FLT_MAX;
        const float* p = partial + (size_t)b * NCHUNK * R_ + r;
        #pragma unroll
        for (int c = 0; c < NCHUNK; ++c) m = fmaxf(m, p[c * R_]);
        cp[r] = m;
    }
    __syncthreads();
    float p0 = 0.f, p1 = 0.f, p2 = 0.f, p3 = 0.f;
    for (int r = tid; r < R_; r += 256) {
        float v = cp[r];
        p0 = fmaf(v, W_fc[0 * R_ + r], p0);
        p1 = fmaf(v, W_fc[1 * R_ + r], p1);
        p2 = fmaf(v, W_fc[2 * R_ + r], p2);
        p3 = fmaf(v, W_fc[3 * R_ + r], p3);
    }
    #pragma unroll
    for (int off = 32; off > 0; off >>= 1) {
        p0 += __shfl_down(p0, off);
        p1 += __shfl_down(p1, off);
        p2 += __shfl_down(p2, off);
        p3 += __shfl_down(p3, off);
    }
    __shared__ float red[4][4];
    int wv = tid >> 6, lane = tid & 63;
    if (lane == 0) { red[wv][0] = p0; red[wv][1] = p1; red[wv][2] = p2; red[wv][3] = p3; }
    __syncthreads();
    if (tid < 4) {
        a_out[b * L_ + tid] = red[0][tid] + red[1][tid] + red[2][tid] + red[3][tid];
    }
}

// ---------------- One-time weight quad-packing ----------------
// Wp[(qd*3 + g)*512 + rr] = float4{ W[g*512+rr][4qd..4qd+3] } where W = merged [W_ih | W_hh]
// along k (x part k<104 from W_ih, h part from W_hh). 104 = 26 quads exactly, no straddle.
__global__ void k_pack(const float* __restrict__ Wih, const float* __restrict__ Whh,
                       float4* __restrict__ Wp) {
    int qd = blockIdx.x;    // 0..153
    int rr = threadIdx.x;   // 0..511
    #pragma unroll
    for (int g = 0; g < 3; ++g) {
        int row = g * 512 + rr;
        float4 v;
        if (qd < XQ_) v = *(const float4*)(Wih + (size_t)row * KX_ + 4 * qd);
        else          v = *(const float4*)(Whh + (size_t)row * R_  + 4 * (qd - XQ_));
        Wp[((size_t)qd * 3 + g) * 512 + rr] = v;
    }
}

// ---------------- Fused per-step: pre (bmi head) + GRU cell ----------------
// grid (R/64=8, B/4=32), block 1024 = 16 waves.
// Pre phase: waves 0..3 do head+xcat for one batch each; waves 4..7 stage h rows to LDS.
// GEMM phase: wave w handles K-quad chunk [(154w)>>4, (154(w+1))>>4) for ALL 4 batches
// (register tile) x 64 rr x 3 gates, dwordx4 packed weight loads.
// Then 4-round LDS tree reduction across the 16 K-chunks; wave 0 does activations.
__global__ void __launch_bounds__(1024, 1) k_step(
        const float* __restrict__ h, const float* __restrict__ W_reg,
        const float* __restrict__ b_reg, const float* __restrict__ a_vec,
        const float* __restrict__ featEmbed, const float* __restrict__ labelsEmbed,
        const int* __restrict__ mask, const float* __restrict__ emb_table,
        const float4* __restrict__ Wp, const float* __restrict__ b_ih,
        const float* __restrict__ b_hh,
        int t, float* __restrict__ h_out, float* __restrict__ out) {
    int tid = threadIdx.x;
    int lane = tid & 63;
    int w = tid >> 6;        // 0..15 = K-chunk
    int b0 = blockIdx.y * 4;
    int rr = blockIdx.x * 64 + lane;

    __shared__ __align__(16) float xs[4][KX_];   // xcat rows for 4 batches
    __shared__ __align__(16) float hs[4][R_];    // h rows for 4 batches
    __shared__ float red[8][64][17];             // padded: conflict-free b32

    // ---- staging: waves 4..7 copy h rows into LDS ----
    if (w >= 4 && w < 8) {
        int bi = w - 4;
        const float4* src = (const float4*)(h + (size_t)(b0 + bi) * R_);
        float4* dst = (float4*)hs[bi];
        dst[lane] = src[lane];
        dst[lane + 64] = src[lane + 64];
    }

    // ---- pre phase: waves 0..3, one batch each ----
    if (w < 4) {
        int bp = b0 + w;
        const float* hb = h + (size_t)bp * R_;
        float p0 = 0.f, p1 = 0.f, p2 = 0.f, p3 = 0.f;
        #pragma unroll
        for (int r = lane; r < R_; r += 64) {
            float v = hb[r];
            p0 = fmaf(v, W_reg[r], p0);
            p1 = fmaf(v, W_reg[512 + r], p1);
            p2 = fmaf(v, W_reg[1024 + r], p2);
            p3 = fmaf(v, W_reg[1536 + r], p3);
        }
        #pragma unroll
        for (int off = 32; off > 0; off >>= 1) {
            p0 += __shfl_down(p0, off);
            p1 += __shfl_down(p1, off);
            p2 += __shfl_down(p2, off);
            p3 += __shfl_down(p3, off);
        }
        p0 = __shfl(p0, 0); p1 = __shfl(p1, 0); p2 = __shfl(p2, 0); p3 = __shfl(p3, 0);
        float bh[4];
        bh[0] = p0 + b_reg[0] + a_vec[bp * 4 + 0];
        bh[1] = p1 + b_reg[1] + a_vec[bp * 4 + 1];
        bh[2] = p2 + b_reg[2] + a_vec[bp * 4 + 2];
        bh[3] = p3 + b_reg[3] + a_vec[bp * 4 + 3];
        float pr[4];
        #pragma unroll
        for (int l = 0; l < 4; ++l) pr[l] = sigmoidf(bh[l]);
        int best = 0;
        float bv = pr[0];
        #pragma unroll
        for (int l = 1; l < 4; ++l) {
            if (pr[l] > bv) { bv = pr[l]; best = l; }  // first-max, matches np argmax
        }
        int ld = c_remap[best];
        if (blockIdx.x == 0 && lane == 0) {
            out[t * B_ + bp] = (float)best;
            #pragma unroll
            for (int l = 0; l < 4; ++l) {
                out[1024 + (t * B_ + bp) * 4 + l] = pr[l];
                out[5120 + (t * B_ + bp) * 4 + l] = bh[l];
            }
            out[9216 + t * B_ + bp] = (float)ld;
        }
        if (lane < E_) {
            xs[w][lane] = featEmbed[bp * (T_ * E_) + t * E_ + lane];
            int m = mask[bp * T_ + t];
            xs[w][E_ + lane] = m ? labelsEmbed[bp * (T_ * E_) + t * E_ + lane]
                                 : emb_table[ld * E_ + lane];
        }
    }
    __syncthreads();

    // ---- GEMM phase: K-chunk per wave, 4-batch register tile ----
    // acc[j], j = type*4 + bi; type: 0=r 1=z 2=i_n(x-part) 3=h_n(h-part)
    float acc[16];
    #pragma unroll
    for (int j = 0; j < 16; ++j) acc[j] = 0.f;

    int q0 = (NQ_ * w) >> 4;
    int q1 = (NQ_ * (w + 1)) >> 4;
    const float4* wp0 = Wp + (size_t)q0 * 1536 + rr;

    int xe = min(q1, XQ_);
    #pragma unroll 2
    for (int qd = q0; qd < xe; ++qd) {
        float4 wr = wp0[0];
        float4 wz = wp0[512];
        float4 wn = wp0[1024];
        wp0 += 1536;
        #pragma unroll
        for (int bi = 0; bi < 4; ++bi) {
            float4 xv = *(const float4*)&xs[bi][4 * qd];
            acc[0 + bi]  = dot4(wr, xv, acc[0 + bi]);
            acc[4 + bi]  = dot4(wz, xv, acc[4 + bi]);
            acc[8 + bi]  = dot4(wn, xv, acc[8 + bi]);
        }
    }
    int hq0 = max(q0, XQ_);
    #pragma unroll 2
    for (int qd = hq0; qd < q1; ++qd) {
        float4 wr = wp0[0];
        float4 wz = wp0[512];
        float4 wn = wp0[1024];
        wp0 += 1536;
        int hq = 4 * (qd - XQ_);
        #pragma unroll
        for (int bi = 0; bi < 4; ++bi) {
            float4 xv = *(const float4*)&hs[bi][hq];
            acc[0 + bi]  = dot4(wr, xv, acc[0 + bi]);
            acc[4 + bi]  = dot4(wz, xv, acc[4 + bi]);
            acc[12 + bi] = dot4(wn, xv, acc[12 + bi]);
        }
    }

    // ---- cross-wave tree reduction (16 -> 1), 4 rounds, slot reuse is race-free:
    // each round's writer re-writes only the slot it alone just read. ----
    if (w >= 8) {
        float* d = red[w - 8][lane];
        #pragma unroll
        for (int j = 0; j < 16; ++j) d[j] = acc[j];
    }
    __syncthreads();
    if (w < 8) {
        const float* s = red[w][lane];
        #pragma unroll
        for (int j = 0; j < 16; ++j) acc[j] += s[j];
    }
    if (w >= 4 && w < 8) {
        float* d = red[w][lane];
        #pragma unroll
        for (int j = 0; j < 16; ++j) d[j] = acc[j];
    }
    __syncthreads();
    if (w < 4) {
        const float* s = red[w + 4][lane];
        #pragma unroll
        for (int j = 0; j < 16; ++j) acc[j] += s[j];
    }
    if (w >= 2 && w < 4) {
        float* d = red[w][lane];
        #pragma unroll
        for (int j = 0; j < 16; ++j) d[j] = acc[j];
    }
    __syncthreads();
    if (w < 2) {
        const float* s = red[w + 2][lane];
        #pragma unroll
        for (int j = 0; j < 16; ++j) acc[j] += s[j];
    }
    if (w == 1) {
        float* d = red[1][lane];
        #pragma unroll
        for (int j = 0; j < 16; ++j) d[j] = acc[j];
    }
    __syncthreads();
    if (w == 0) {
        const float* s = red[1][lane];
        #pragma unroll
        for (int j = 0; j < 16; ++j) acc[j] += s[j];
        float bir = b_ih[rr],        bhr = b_hh[rr];
        float biz = b_ih[512 + rr],  bhz = b_hh[512 + rr];
        float bin = b_ih[1024 + rr], bhn = b_hh[1024 + rr];
        #pragma unroll
        for (int bi = 0; bi < 4; ++bi) {
            float r = sigmoidf(acc[0 + bi] + bir + bhr);
            float z = sigmoidf(acc[4 + bi] + biz + bhz);
            float n = tanhf(acc[8 + bi] + bin + r * (acc[12 + bi] + bhn));
            h_out[(size_t)(b0 + bi) * R_ + rr] = (1.0f - z) * n + z * hs[bi][rr];
        }
    }
}

extern "C" void kernel_launch(void* const* d_in, const int* in_sizes, int n_in,
                              void* d_out, int out_size, void* d_ws, size_t ws_size,
                              hipStream_t stream) {
    const float* featEmbed   = (const float*)d_in[0];
    const float* labelsEmbed = (const float*)d_in[1];
    const float* enc         = (const float*)d_in[2];
    const float* h_n         = (const float*)d_in[3];
    const int*   mask        = (const int*)d_in[4];
    const int*   enc_len     = (const int*)d_in[5];
    const float* emb_table   = (const float*)d_in[6];
    const float* W_fc        = (const float*)d_in[7];
    const float* W_reg       = (const float*)d_in[8];
    const float* b_reg       = (const float*)d_in[9];
    const float* W_ih        = (const float*)d_in[10];
    const float* W_hh        = (const float*)d_in[11];
    const float* b_ih        = (const float*)d_in[12];
    const float* b_hh        = (const float*)d_in[13];
    float* out = (float*)d_out;

    // workspace layout (floats); total ~2.13M floats = ~8.5 MB
    float* ws      = (float*)d_ws;
    float* partial = ws;                          // B*NCHUNK*R = 1048576 (16B-aligned)
    float* Wp      = partial + B_ * NCHUNK * R_;  // NQ*3*R*4 = 946176 (16B-aligned)
    float* h0      = Wp + NQ_ * 3 * R_ * 4;       // B*R = 65536
    float* h1      = h0 + B_ * R_;                // B*R = 65536
    float* a_vec   = h1 + B_ * R_;                // B*L = 512

    k_pack<<<dim3(NQ_), 512, 0, stream>>>(W_ih, W_hh, (float4*)Wp);
    k_maxpool<<<dim3(NCHUNK, B_), 128, 0, stream>>>(enc, enc_len, (float4*)partial);
    k_pool_a<<<B_, 256, 0, stream>>>(partial, W_fc, a_vec);

    const float* hcur = h_n;
    for (int t = 0; t < T_; ++t) {
        float* hnext = (t & 1) ? h1 : h0;
        k_step<<<dim3(R_ / 64, B_ / 4), 1024, 0, stream>>>(
            hcur, W_reg, b_reg, a_vec, featEmbed, labelsEmbed, mask, emb_table,
            (const float4*)Wp, b_ih, b_hh, t, hnext, out);
        hcur = hnext;
    }
}

// Round 2
// 765.365 us; speedup vs baseline: 1.1465x; 1.0112x over previous
//
#include <hip/hip_runtime.h>
#include <float.h>
#include <math.h>

// Decoder3: ragged maxpool -> a; then T=8 sequential fused GRU-decoder steps.
// B=128 T=8 E=52 S=2048 R=512 L=4.
// Outputs (f32, concat): dec_output[T*B] | dec_prob[T*B*L] | disc_input[T*B*L] | kl_input[T*B]
//
// R2: k_step was L2-BW bound on weight refetch (473 KB/CU/step). Now 8-batch register
// tile with rr-slice 32: lane = (rr in 32, batch-half in 2), half-wave weight loads
// coalesce to the same cachelines -> unique L2 traffic halves to 236 KB/CU/step.
// k_pack merged into the maxpool launch (independent work, one fewer dispatch).

#define B_ 128
#define T_ 8
#define E_ 52
#define S_ 2048
#define R_ 512
#define L_ 4
#define GR_ 1536   // 3R
#define KX_ 104    // 2E
#define NCHUNK 16
#define SCHUNK (S_ / NCHUNK)   // 128
#define NQ_ 154    // merged K=616 in quads of 4
#define XQ_ 26     // x-part quads (104/4); quads >= XQ_ are h-part

__device__ __constant__ int c_remap[4] = {175, 176, 44, 173};

__device__ __forceinline__ float sigmoidf(float x) { return 1.0f / (1.0f + expf(-x)); }
__device__ __forceinline__ float dot4(float4 w, float4 x, float a) {
    a = fmaf(w.x, x.x, a);
    a = fmaf(w.y, x.y, a);
    a = fmaf(w.z, x.z, a);
    a = fmaf(w.w, x.w, a);
    return a;
}

// ---------------- Phase 1: ragged max-pool (chunked) + one-time weight quad-pack ----
// 1D grid: blocks [0, NCHUNK*B_) do maxpool chunk (c = idx&15, b = idx>>4);
// blocks [NCHUNK*B_, NCHUNK*B_+NQ_) pack quad qd of the merged [W_ih | W_hh]:
// Wp[(qd*3+g)*512 + rr] = float4{ W[g*512+rr][4qd..4qd+3] }. 104 = 26 quads, no straddle.
__global__ void k_pool_pack(const float* __restrict__ enc, const int* __restrict__ enc_len,
                            float4* __restrict__ partial,
                            const float* __restrict__ Wih, const float* __restrict__ Whh,
                            float4* __restrict__ Wp) {
    int idx = blockIdx.x;
    int tid = threadIdx.x;  // 0..127
    if (idx >= NCHUNK * B_) {
        int qd = idx - NCHUNK * B_;
        #pragma unroll
        for (int i = 0; i < 4; ++i) {
            int rr = tid + 128 * i;
            #pragma unroll
            for (int g = 0; g < 3; ++g) {
                int row = g * 512 + rr;
                float4 v;
                if (qd < XQ_) v = *(const float4*)(Wih + (size_t)row * KX_ + 4 * qd);
                else          v = *(const float4*)(Whh + (size_t)row * R_  + 4 * (qd - XQ_));
                Wp[((size_t)qd * 3 + g) * 512 + rr] = v;
            }
        }
        return;
    }
    int c = idx & (NCHUNK - 1);
    int b = idx >> 4;
    int len = enc_len[b];
    int s0 = c * SCHUNK;
    int s1 = min(s0 + SCHUNK, len);
    float4 m = make_float4(-FLT_MAX, -FLT_MAX, -FLT_MAX, -FLT_MAX);
    const float4* base = (const float4*)(enc + (size_t)b * S_ * R_);
    for (int s = s0; s < s1; ++s) {
        float4 v = base[(size_t)s * (R_ / 4) + tid];
        m.x = fmaxf(m.x, v.x);
        m.y = fmaxf(m.y, v.y);
        m.z = fmaxf(m.z, v.z);
        m.w = fmaxf(m.w, v.w);
    }
    partial[((size_t)b * NCHUNK + c) * (R_ / 4) + tid] = m;
}

// ---------------- Phase 1b: reduce partials + a = code_pool @ W_fc.T ----------------
__global__ void k_pool_a(const float* __restrict__ partial, const float* __restrict__ W_fc,
                         float* __restrict__ a_out) {
    int b = blockIdx.x;
    int tid = threadIdx.x;
    __shared__ float cp[R_];
    for (int r = tid; r < R_; r += 256) {
        float m = -FLT_MAX;
        const float* p = partial + (size_t)b * NCHUNK * R_ + r;
        #pragma unroll
        for (int c = 0; c < NCHUNK; ++c) m = fmaxf(m, p[c * R_]);
        cp[r] = m;
    }
    __syncthreads();
    float p0 = 0.f, p1 = 0.f, p2 = 0.f, p3 = 0.f;
    for (int r = tid; r < R_; r += 256) {
        float v = cp[r];
        p0 = fmaf(v, W_fc[0 * R_ + r], p0);
        p1 = fmaf(v, W_fc[1 * R_ + r], p1);
        p2 = fmaf(v, W_fc[2 * R_ + r], p2);
        p3 = fmaf(v, W_fc[3 * R_ + r], p3);
    }
    #pragma unroll
    for (int off = 32; off > 0; off >>= 1) {
        p0 += __shfl_down(p0, off);
        p1 += __shfl_down(p1, off);
        p2 += __shfl_down(p2, off);
        p3 += __shfl_down(p3, off);
    }
    __shared__ float red[4][4];
    int wv = tid >> 6, lane = tid & 63;
    if (lane == 0) { red[wv][0] = p0; red[wv][1] = p1; red[wv][2] = p2; red[wv][3] = p3; }
    __syncthreads();
    if (tid < 4) {
        a_out[b * L_ + tid] = red[0][tid] + red[1][tid] + red[2][tid] + red[3][tid];
    }
}

// ---------------- Fused per-step: pre (bmi head) + GRU cell ----------------
// grid (R/32=16, B/8=16), block 1024 = 16 waves.
// Pre phase: waves 0..7 do head+xcat for one batch each; waves 8..15 stage h rows to LDS.
// GEMM phase: wave w = K-quad chunk [(154w)>>4, (154(w+1))>>4); lane = (rr = lane&31,
// batch-half = lane>>5). Each lane accumulates 4 gate-types x 4 batches (its half);
// the two half-waves load identical weight cachelines (L1-broadcast) so unique L2
// traffic is 32 rr x 3 gates x 616 K x 4B = 236 KB/block/step.
// Then 4-round LDS tree reduction across the 16 K-chunks; wave 0 does activations.
__global__ void __launch_bounds__(1024, 1) k_step(
        const float* __restrict__ h, const float* __restrict__ W_reg,
        const float* __restrict__ b_reg, const float* __restrict__ a_vec,
        const float* __restrict__ featEmbed, const float* __restrict__ labelsEmbed,
        const int* __restrict__ mask, const float* __restrict__ emb_table,
        const float4* __restrict__ Wp, const float* __restrict__ b_ih,
        const float* __restrict__ b_hh,
        int t, float* __restrict__ h_out, float* __restrict__ out) {
    int tid = threadIdx.x;
    int lane = tid & 63;
    int w = tid >> 6;        // 0..15 = K-chunk
    int b0 = blockIdx.y * 8;
    int rrl = lane & 31;
    int bh = lane >> 5;                 // batch half: handles b0 + bh*4 .. +3
    int rr = blockIdx.x * 32 + rrl;     // global output row in [0,512)

    __shared__ __align__(16) float xs[8][KX_];   // xcat rows for 8 batches
    __shared__ __align__(16) float hs[8][R_];    // h rows for 8 batches
    __shared__ float red[8][64][17];             // padded: conflict-free b32

    // ---- staging: waves 8..15 copy h rows into LDS ----
    if (w >= 8) {
        int bi = w - 8;
        const float4* src = (const float4*)(h + (size_t)(b0 + bi) * R_);
        float4* dst = (float4*)hs[bi];
        dst[lane] = src[lane];
        dst[lane + 64] = src[lane + 64];
    }

    // ---- pre phase: waves 0..7, one batch each ----
    if (w < 8) {
        int bp = b0 + w;
        const float* hb = h + (size_t)bp * R_;
        float p0 = 0.f, p1 = 0.f, p2 = 0.f, p3 = 0.f;
        #pragma unroll
        for (int r = lane; r < R_; r += 64) {
            float v = hb[r];
            p0 = fmaf(v, W_reg[r], p0);
            p1 = fmaf(v, W_reg[512 + r], p1);
            p2 = fmaf(v, W_reg[1024 + r], p2);
            p3 = fmaf(v, W_reg[1536 + r], p3);
        }
        #pragma unroll
        for (int off = 32; off > 0; off >>= 1) {
            p0 += __shfl_down(p0, off);
            p1 += __shfl_down(p1, off);
            p2 += __shfl_down(p2, off);
            p3 += __shfl_down(p3, off);
        }
        p0 = __shfl(p0, 0); p1 = __shfl(p1, 0); p2 = __shfl(p2, 0); p3 = __shfl(p3, 0);
        float bh_[4];
        bh_[0] = p0 + b_reg[0] + a_vec[bp * 4 + 0];
        bh_[1] = p1 + b_reg[1] + a_vec[bp * 4 + 1];
        bh_[2] = p2 + b_reg[2] + a_vec[bp * 4 + 2];
        bh_[3] = p3 + b_reg[3] + a_vec[bp * 4 + 3];
        float pr[4];
        #pragma unroll
        for (int l = 0; l < 4; ++l) pr[l] = sigmoidf(bh_[l]);
        int best = 0;
        float bv = pr[0];
        #pragma unroll
        for (int l = 1; l < 4; ++l) {
            if (pr[l] > bv) { bv = pr[l]; best = l; }  // first-max, matches np argmax
        }
        int ld = c_remap[best];
        if (blockIdx.x == 0 && lane == 0) {
            out[t * B_ + bp] = (float)best;
            #pragma unroll
            for (int l = 0; l < 4; ++l) {
                out[1024 + (t * B_ + bp) * 4 + l] = pr[l];
                out[5120 + (t * B_ + bp) * 4 + l] = bh_[l];
            }
            out[9216 + t * B_ + bp] = (float)ld;
        }
        if (lane < E_) {
            xs[w][lane] = featEmbed[bp * (T_ * E_) + t * E_ + lane];
            int m = mask[bp * T_ + t];
            xs[w][E_ + lane] = m ? labelsEmbed[bp * (T_ * E_) + t * E_ + lane]
                                 : emb_table[ld * E_ + lane];
        }
    }
    __syncthreads();

    // ---- GEMM phase: K-chunk per wave, 8-batch tile (4 per lane-half) ----
    // acc[j], j = type*4 + i; type: 0=r 1=z 2=i_n(x-part) 3=h_n(h-part); batch = b0+bh*4+i
    float acc[16];
    #pragma unroll
    for (int j = 0; j < 16; ++j) acc[j] = 0.f;

    int q0 = (NQ_ * w) >> 4;
    int q1 = (NQ_ * (w + 1)) >> 4;
    const float4* wp0 = Wp + (size_t)q0 * 1536 + rr;

    int xe = min(q1, XQ_);
    #pragma unroll 2
    for (int qd = q0; qd < xe; ++qd) {
        float4 wr = wp0[0];
        float4 wz = wp0[512];
        float4 wn = wp0[1024];
        wp0 += 1536;
        #pragma unroll
        for (int i = 0; i < 4; ++i) {
            float4 xv = *(const float4*)&xs[bh * 4 + i][4 * qd];
            acc[0 + i] = dot4(wr, xv, acc[0 + i]);
            acc[4 + i] = dot4(wz, xv, acc[4 + i]);
            acc[8 + i] = dot4(wn, xv, acc[8 + i]);
        }
    }
    int hq0 = max(q0, XQ_);
    #pragma unroll 2
    for (int qd = hq0; qd < q1; ++qd) {
        float4 wr = wp0[0];
        float4 wz = wp0[512];
        float4 wn = wp0[1024];
        wp0 += 1536;
        int hq = 4 * (qd - XQ_);
        #pragma unroll
        for (int i = 0; i < 4; ++i) {
            float4 xv = *(const float4*)&hs[bh * 4 + i][hq];
            acc[0 + i]  = dot4(wr, xv, acc[0 + i]);
            acc[4 + i]  = dot4(wz, xv, acc[4 + i]);
            acc[12 + i] = dot4(wn, xv, acc[12 + i]);
        }
    }

    // ---- cross-wave tree reduction (16 -> 1), 4 rounds, slot reuse is race-free:
    // each round's writer re-writes only the slot it alone just read. ----
    if (w >= 8) {
        float* d = red[w - 8][lane];
        #pragma unroll
        for (int j = 0; j < 16; ++j) d[j] = acc[j];
    }
    __syncthreads();
    if (w < 8) {
        const float* s = red[w][lane];
        #pragma unroll
        for (int j = 0; j < 16; ++j) acc[j] += s[j];
    }
    if (w >= 4 && w < 8) {
        float* d = red[w][lane];
        #pragma unroll
        for (int j = 0; j < 16; ++j) d[j] = acc[j];
    }
    __syncthreads();
    if (w < 4) {
        const float* s = red[w + 4][lane];
        #pragma unroll
        for (int j = 0; j < 16; ++j) acc[j] += s[j];
    }
    if (w >= 2 && w < 4) {
        float* d = red[w][lane];
        #pragma unroll
        for (int j = 0; j < 16; ++j) d[j] = acc[j];
    }
    __syncthreads();
    if (w < 2) {
        const float* s = red[w + 2][lane];
        #pragma unroll
        for (int j = 0; j < 16; ++j) acc[j] += s[j];
    }
    if (w == 1) {
        float* d = red[1][lane];
        #pragma unroll
        for (int j = 0; j < 16; ++j) d[j] = acc[j];
    }
    __syncthreads();
    if (w == 0) {
        const float* s = red[1][lane];
        #pragma unroll
        for (int j = 0; j < 16; ++j) acc[j] += s[j];
        float bir = b_ih[rr],        bhr = b_hh[rr];
        float biz = b_ih[512 + rr],  bhz = b_hh[512 + rr];
        float bin = b_ih[1024 + rr], bhn = b_hh[1024 + rr];
        #pragma unroll
        for (int i = 0; i < 4; ++i) {
            int bi = bh * 4 + i;
            float r = sigmoidf(acc[0 + i] + bir + bhr);
            float z = sigmoidf(acc[4 + i] + biz + bhz);
            float n = tanhf(acc[8 + i] + bin + r * (acc[12 + i] + bhn));
            h_out[(size_t)(b0 + bi) * R_ + rr] = (1.0f - z) * n + z * hs[bi][rr];
        }
    }
}

extern "C" void kernel_launch(void* const* d_in, const int* in_sizes, int n_in,
                              void* d_out, int out_size, void* d_ws, size_t ws_size,
                              hipStream_t stream) {
    const float* featEmbed   = (const float*)d_in[0];
    const float* labelsEmbed = (const float*)d_in[1];
    const float* enc         = (const float*)d_in[2];
    const float* h_n         = (const float*)d_in[3];
    const int*   mask        = (const int*)d_in[4];
    const int*   enc_len     = (const int*)d_in[5];
    const float* emb_table   = (const float*)d_in[6];
    const float* W_fc        = (const float*)d_in[7];
    const float* W_reg       = (const float*)d_in[8];
    const float* b_reg       = (const float*)d_in[9];
    const float* W_ih        = (const float*)d_in[10];
    const float* W_hh        = (const float*)d_in[11];
    const float* b_ih        = (const float*)d_in[12];
    const float* b_hh        = (const float*)d_in[13];
    float* out = (float*)d_out;

    // workspace layout (floats); total ~2.13M floats = ~8.5 MB
    float* ws      = (float*)d_ws;
    float* partial = ws;                          // B*NCHUNK*R = 1048576 (16B-aligned)
    float* Wp      = partial + B_ * NCHUNK * R_;  // NQ*3*R*4 = 946176 (16B-aligned)
    float* h0      = Wp + NQ_ * 3 * R_ * 4;       // B*R = 65536
    float* h1      = h0 + B_ * R_;                // B*R = 65536
    float* a_vec   = h1 + B_ * R_;                // B*L = 512

    k_pool_pack<<<dim3(NCHUNK * B_ + NQ_), 128, 0, stream>>>(
        enc, enc_len, (float4*)partial, W_ih, W_hh, (float4*)Wp);
    k_pool_a<<<B_, 256, 0, stream>>>(partial, W_fc, a_vec);

    const float* hcur = h_n;
    for (int t = 0; t < T_; ++t) {
        float* hnext = (t & 1) ? h1 : h0;
        k_step<<<dim3(R_ / 32, B_ / 8), 1024, 0, stream>>>(
            hcur, W_reg, b_reg, a_vec, featEmbed, labelsEmbed, mask, emb_table,
            (const float4*)Wp, b_ih, b_hh, t, hnext, out);
        hcur = hnext;
    }
}